// Round 17
// baseline (145.508 us; speedup 1.0000x reference)
//
#include <hip/hip_runtime.h>
#include <hip/hip_fp16.h>

#define BB 16384
#define LL 200
#define DD 100
#define VV 100000
#define CHUNK  50000           // f16 entries per LDS chunk: 100,000 B
#define CI4    6250            // int4 per chunk (50000*2/16)
#define NCHUNK 2
#define PBLK   256             // pool blocks: 1/CU (100KB LDS), ALL 256 CUs
#define PTHR   1024            // 16 waves/block
#define RPW    4               // rows per wave: 64 rows/block / 16 waves
#define REP1   16              // rowdot reps (instrumentation)
#define REP2   8               // pool reps (instrumentation)

// INSTRUMENTATION ROUND (sacrificial): both kernels repeat their own work
// with bijectively rotated assignments -> identical outputs every rep,
// real repeated memory traffic, dispatch durations exceed the ~40us harness
// fills so rocprof top-5 shows OUR kernels with counters.

// Kernel 1 (R16 math, x16 rotated): rowdot[v] = sum_d E[v,d]*w[d] as f16.
__global__ __launch_bounds__(256) void rowdot_kernel(const float4* __restrict__ E4,
                                                     const float4* __restrict__ w4,
                                                     __half* __restrict__ rowdot) {
    const int tid  = blockIdx.x * blockDim.x + threadIdx.x;
    const int wave = tid >> 6;
    const int lane = threadIdx.x & 63;
    const int half = lane >> 5;
    const int sub  = lane & 31;

    float4 wv = make_float4(0.f, 0.f, 0.f, 0.f);
    if (sub < 25) wv = w4[sub];

    const int r0 = wave * 2 + half;
    #pragma unroll 1
    for (int rep = 0; rep < REP1; ++rep) {
        int r = r0 + rep * 6250;          // bijective shift mod VV
        if (r >= VV) r -= VV;
        float s = 0.0f;
        if (sub < 25) {
            float4 v = E4[(size_t)r * 25 + sub];
            s = v.x * wv.x + v.y * wv.y + v.z * wv.z + v.w * wv.w;
        }
        #pragma unroll
        for (int off = 16; off > 0; off >>= 1)
            s += __shfl_xor(s, off, 64);
        if (sub == 0) rowdot[r] = __float2half(s);
    }
}

// Kernel 2 (R16 structure, x8 rotated block->rowgroup assignment).
__global__ __launch_bounds__(1024) void pool_kernel(const int4* __restrict__ idx4,
                                                    const __half* __restrict__ rowdot,
                                                    float* __restrict__ out) {
    __shared__ __half sh[CHUNK];
    const int t    = threadIdx.x;
    const int wv   = t >> 6;
    const int lane = t & 63;
    const bool act = lane < 50;
    const int4* src = (const int4*)rowdot;

    #pragma unroll 1
    for (int rep = 0; rep < REP2; ++rep) {
        const int bg   = (blockIdx.x + rep * 37) & 255;   // bijective in blocks
        const int row0 = bg * 64 + wv * RPW;

        int4 pf[RPW];
        #pragma unroll
        for (int r = 0; r < RPW; ++r)
            pf[r] = act ? idx4[(size_t)(row0 + r) * 50 + lane]
                        : make_int4(0, 0, 0, 0);

        float acc[RPW] = {0.f, 0.f, 0.f, 0.f};

        #pragma unroll 1
        for (int c = 0; c < NCHUNK; ++c) {
            const int base = c * CHUNK;
            __syncthreads();   // previous readers done before overwrite
            #pragma unroll
            for (int j = 0; j < 7; ++j) {
                const int k = j * PTHR + t;
                if (k < CI4) {
                    const int4* gp = src + c * CI4 + k;             // per-lane
                    char* lb = (char*)sh + j * 16384 + wv * 1024;   // wave-uniform
                    __builtin_amdgcn_global_load_lds(
                        (const __attribute__((address_space(1))) void*)gp,
                        (__attribute__((address_space(3))) void*)lb,
                        16, 0, 0);
                }
            }
            __syncthreads();   // drain -> staged data visible
            if (act) {
                #pragma unroll
                for (int r = 0; r < RPW; ++r) {
                    int4 i4 = pf[r];
                    int a0 = i4.x - base, a1 = i4.y - base;
                    int a2 = i4.z - base, a3 = i4.w - base;
                    if ((unsigned)a0 < (unsigned)CHUNK) acc[r] += __half2float(sh[a0]);
                    if ((unsigned)a1 < (unsigned)CHUNK) acc[r] += __half2float(sh[a1]);
                    if ((unsigned)a2 < (unsigned)CHUNK) acc[r] += __half2float(sh[a2]);
                    if ((unsigned)a3 < (unsigned)CHUNK) acc[r] += __half2float(sh[a3]);
                }
            }
        }

        #pragma unroll
        for (int r = 0; r < RPW; ++r) {
            float s = acc[r];
            #pragma unroll
            for (int off = 32; off > 0; off >>= 1)
                s += __shfl_xor(s, off, 64);
            if (lane == 0) out[row0 + r] = s * (1.0f / LL);  // same value each rep
        }
    }
}

extern "C" void kernel_launch(void* const* d_in, const int* in_sizes, int n_in,
                              void* d_out, int out_size, void* d_ws, size_t ws_size,
                              hipStream_t stream) {
    const int4*   idx4   = (const int4*)d_in[0];
    const float4* E4     = (const float4*)d_in[1];
    const float4* w4     = (const float4*)d_in[2];
    float*        out    = (float*)d_out;
    __half*       rowdot = (__half*)d_ws;

    rowdot_kernel<<<VV / 8, 256, 0, stream>>>(E4, w4, rowdot);
    pool_kernel<<<PBLK, PTHR, 0, stream>>>(idx4, rowdot, out);
}

// Round 18
// 43.194 us; speedup vs baseline: 3.3687x; 3.3687x over previous
//
#include <hip/hip_runtime.h>
#include <hip/hip_fp16.h>

#define BB 16384
#define LL 200
#define DD 100
#define VV 100000
#define CHUNK  50000           // f16 entries per LDS chunk: 100,000 B
#define CI4    6250            // int4 per chunk (50000*2/16)
#define NCHUNK 2
#define FBLK   256             // 1 block/CU (100KB LDS) -> co-residency guaranteed
#define FTHR   1024            // 16 waves/block
#define RPW    4               // pool rows per wave: 64 rows/block / 16 waves
#define PAIRS_PER_BLK 196      // rowdot pairs/block: 196*256 = 50176 >= 50000

// ONE fused kernel. Phase 1: rowdot slice (half-wave per row, f16-packed
// stores). Custom 256-block barrier (1 block/CU => co-resident; cg::sync at
// 2048 blocks cost ~200us in R5 — this is 256 same-address atomics, ~1-2us).
// Phase 2: R16-proven async-staged LDS gather. idx preloaded BEFORE phase 1
// so its 13MB HBM read overlaps the 40MB E read (rowdot runs at ~50% BW).
__global__ __launch_bounds__(1024) void fused_kernel(const int4* __restrict__ idx4,
                                                     const float4* __restrict__ E4,
                                                     const float4* __restrict__ w4,
                                                     __half* __restrict__ rowdot,
                                                     int* __restrict__ bar,
                                                     float* __restrict__ out) {
    __shared__ __half sh[CHUNK];
    const int t    = threadIdx.x;
    const int wv   = t >> 6;                 // wave 0..15
    const int lane = t & 63;
    const int half = lane >> 5;
    const int sub  = lane & 31;
    const bool act = lane < 50;
    const int row0 = blockIdx.x * 64 + wv * RPW;

    // ---- issue pool idx loads FIRST (13MB overlaps phase-1's E read)
    int4 pf[RPW];
    #pragma unroll
    for (int r = 0; r < RPW; ++r)
        pf[r] = act ? idx4[(size_t)(row0 + r) * 50 + lane]
                    : make_int4(0, 0, 0, 0);

    // ---- phase 1: rowdot pairs [blk*196, blk*196+196)
    float4 wvf = make_float4(0.f, 0.f, 0.f, 0.f);
    if (sub < 25) wvf = w4[sub];
    const int p0 = blockIdx.x * PAIRS_PER_BLK;
    #pragma unroll 1
    for (int i = wv; i < PAIRS_PER_BLK; i += 16) {
        const int p = p0 + i;
        if (p < VV / 2) {
            const int r = p * 2 + half;
            float s = 0.0f;
            if (sub < 25) {
                float4 v = E4[(size_t)r * 25 + sub];
                s = v.x * wvf.x + v.y * wvf.y + v.z * wvf.z + v.w * wvf.w;
            }
            #pragma unroll
            for (int off = 16; off > 0; off >>= 1)
                s += __shfl_xor(s, off, 64);
            float s1 = __shfl(s, 32, 64);    // UNIFORM exec (R13 lesson)
            if (lane == 0) {
                unsigned u0 = __half_as_ushort(__float2half(s));
                unsigned u1 = __half_as_ushort(__float2half(s1));
                ((unsigned*)rowdot)[p] = u0 | (u1 << 16);
            }
        }
    }

    // ---- device barrier: all table writes visible to all XCDs
    __syncthreads();                          // block's stores issued
    if (t == 0) {
        __hip_atomic_fetch_add(bar, 1, __ATOMIC_RELEASE, __HIP_MEMORY_SCOPE_AGENT);
        while (__hip_atomic_load(bar, __ATOMIC_ACQUIRE, __HIP_MEMORY_SCOPE_AGENT) < FBLK)
            __builtin_amdgcn_s_sleep(2);
        __threadfence();                      // acquire: invalidate stale L1/L2
    }
    __syncthreads();

    // ---- phase 2 (R16-proven): async-stage table chunks, probe from LDS
    float acc[RPW] = {0.f, 0.f, 0.f, 0.f};
    const int4* src = (const int4*)rowdot;
    #pragma unroll 1
    for (int c = 0; c < NCHUNK; ++c) {
        const int base = c * CHUNK;
        __syncthreads();                      // prev chunk's readers done
        #pragma unroll
        for (int j = 0; j < 7; ++j) {
            const int k = j * FTHR + t;
            if (k < CI4) {
                const int4* gp = src + c * CI4 + k;               // per-lane
                char* lb = (char*)sh + j * 16384 + wv * 1024;     // wave-uniform
                __builtin_amdgcn_global_load_lds(
                    (const __attribute__((address_space(1))) void*)gp,
                    (__attribute__((address_space(3))) void*)lb,
                    16, 0, 0);
            }
        }
        __syncthreads();                      // drain -> staged data visible
        if (act) {
            #pragma unroll
            for (int r = 0; r < RPW; ++r) {
                int4 i4 = pf[r];
                int a0 = i4.x - base, a1 = i4.y - base;
                int a2 = i4.z - base, a3 = i4.w - base;
                if ((unsigned)a0 < (unsigned)CHUNK) acc[r] += __half2float(sh[a0]);
                if ((unsigned)a1 < (unsigned)CHUNK) acc[r] += __half2float(sh[a1]);
                if ((unsigned)a2 < (unsigned)CHUNK) acc[r] += __half2float(sh[a2]);
                if ((unsigned)a3 < (unsigned)CHUNK) acc[r] += __half2float(sh[a3]);
            }
        }
    }

    #pragma unroll
    for (int r = 0; r < RPW; ++r) {
        float s = acc[r];
        #pragma unroll
        for (int off = 32; off > 0; off >>= 1)
            s += __shfl_xor(s, off, 64);
        if (lane == 0) out[row0 + r] = s * (1.0f / LL);
    }
}

extern "C" void kernel_launch(void* const* d_in, const int* in_sizes, int n_in,
                              void* d_out, int out_size, void* d_ws, size_t ws_size,
                              hipStream_t stream) {
    const int4*   idx4   = (const int4*)d_in[0];      // [B, L] int32 as int4
    const float4* E4     = (const float4*)d_in[1];    // [V, D] f32 as float4
    const float4* w4     = (const float4*)d_in[2];    // [D, 1] f32 as float4
    float*        out    = (float*)d_out;             // [B, 1] f32
    __half*       rowdot = (__half*)d_ws;             // 200 KB f16 table
    int*          bar    = (int*)((char*)d_ws + 262144);  // barrier counter

    // counter must be 0 every call (ws is poisoned 0xAA once, never restored)
    hipMemsetAsync(bar, 0, sizeof(int), stream);
    fused_kernel<<<FBLK, FTHR, 0, stream>>>(idx4, E4, w4, rowdot, bar, out);
}